// Round 9
// baseline (98.460 us; speedup 1.0000x reference)
//
#include <hip/hip_runtime.h>
#include <hip/hip_bf16.h>
#include <hip/hip_fp16.h>

// Geometry (compile-time):
//  image 2048x2048 f32 -> conv2x2 stride2 -> hi 1024x1024
//  padded 1449x1449, hi at offset (212,212), center=724
//  out grid 1448x1448, 64 angles (theta = 0..63 radians)
//  A[x][a] = sum_y bilinear_wrap(padded, rot(x,y,a)) ; out = A / max(A)

#define HM 1024
#define PW 1449
#define PWS 1450           // RP row stride (col 1449 duplicates col 0 for x-wrap)
#define PAD0 212
#define OW 1448
#define NA 64
#define NOUT (OW * NA)     // 92672
#define CENTER 724.0f
#define XS_N 181           // 1448/8 x-strips
#define YS 4               // y chunks
#define NWAVES (XS_N * NA * YS)   // 46336
#define NBLOCKS (NWAVES / 4)      // 11584
#define NRP ((size_t)PW * PWS)    // 2,101,050 packed elements
#define NPAD ((size_t)PW * PW)

#ifndef __has_builtin
#define __has_builtin(x) 0
#endif
#if __has_builtin(__builtin_amdgcn_fdot2) && __has_builtin(__builtin_amdgcn_cvt_pkrtz)
#define USE_DOT2 1
typedef _Float16 h2 __attribute__((ext_vector_type(2)));   // fdot2 operand type
__device__ __forceinline__ h2 pkrtz(float a, float b) {
    return __builtin_bit_cast(h2, __builtin_amdgcn_cvt_pkrtz(a, b));
}
#else
#define USE_DOT2 0
#endif

// conv value of padded image at (r,c); 0 outside data square
__device__ __forceinline__ float conv_at(const float* __restrict__ img, int r, int c) {
    int i = r - PAD0;
    int j = c - PAD0;
    if ((unsigned)i >= (unsigned)HM || (unsigned)j >= (unsigned)HM) return 0.0f;
    const float2* r0 = reinterpret_cast<const float2*>(img + (size_t)(2 * i) * 2048);
    const float2* r1 = reinterpret_cast<const float2*>(img + (size_t)(2 * i + 1) * 2048);
    float2 a = r0[j];
    float2 b = r1[j];
    return fmaf(-0.1384f, a.x,
           fmaf( 0.7243f, a.y,
           fmaf(-0.6038f, b.x, 0.1601f * b.y)));
}

// 64-entry cos/sin table (device cosf == what k_proj used before; bit-identical)
__global__ __launch_bounds__(64) void k_trig(float2* __restrict__ cs) {
    int i = threadIdx.x;
    cs[i] = make_float2(cosf((float)i), sinf((float)i));
}

// RP[r*PWS+x] = half2( P[r][x'], P[(r+1)%1449][x'] ), x' = x%1449.
__global__ __launch_bounds__(256) void k_pack(const float* __restrict__ img,
                                              unsigned int* __restrict__ RP) {
    int gid = blockIdx.x * blockDim.x + threadIdx.x;
    if (gid >= (int)NRP) return;
    int r = gid / PWS;
    int x = gid - r * PWS;
    int cx = (x == PW) ? 0 : x;
    int r1 = (r == PW - 1) ? 0 : r + 1;
    float v0 = conv_at(img, r, cx);
    float v1 = conv_at(img, r1, cx);
    __half2 h = __floats2half2_rn(v0, v1);   // low = row r, high = row r+1
    RP[gid] = *reinterpret_cast<unsigned int*>(&h);
}

// 4-tap bilinear blend from one packed uint2. q.x=(v00,v10), q.y=(v01,v11).
__device__ __forceinline__ float blend4(uint2 q, float dx, float dy, float acc) {
#if USE_DOT2
    float omdx = 1.0f - dx;
    float omdy = 1.0f - dy;
    h2 w0 = pkrtz(omdy * omdx, dy * omdx);   // (w00, w10)
    h2 w1 = pkrtz(omdy * dx,   dy * dx);     // (w01, w11)
    acc = __builtin_amdgcn_fdot2(__builtin_bit_cast(h2, q.x), w0, acc, false);
    acc = __builtin_amdgcn_fdot2(__builtin_bit_cast(h2, q.y), w1, acc, false);
    return acc;
#else
    float2 f0 = __half22float2(*reinterpret_cast<const __half2*>(&q.x));
    float2 f1 = __half22float2(*reinterpret_cast<const __half2*>(&q.y));
    float top = fmaf(dx, f1.x - f0.x, f0.x);
    float bot = fmaf(dx, f1.y - f0.y, f0.y);
    return fmaf(dy, bot - top, acc + top);
#endif
}

__device__ __forceinline__ float blend4_val(uint2 q, float dx, float dy) {
#if USE_DOT2
    float omdx = 1.0f - dx;
    float omdy = 1.0f - dy;
    h2 w0 = pkrtz(omdy * omdx, dy * omdx);
    h2 w1 = pkrtz(omdy * dx,   dy * dx);
    float t = __builtin_amdgcn_fdot2(__builtin_bit_cast(h2, q.x), w0, 0.0f, false);
    return __builtin_amdgcn_fdot2(__builtin_bit_cast(h2, q.y), w1, t, false);
#else
    float2 f0 = __half22float2(*reinterpret_cast<const __half2*>(&q.x));
    float2 f1 = __half22float2(*reinterpret_cast<const __half2*>(&q.y));
    float top = fmaf(dx, f1.x - f0.x, f0.x);
    float bot = fmaf(dx, f1.y - f0.y, f0.y);
    return fmaf(dy, bot - top, top);
#endif
}

// interior-path address+fraction for one oct
__device__ __forceinline__ void addr_int(int tb, int oct_beg, float fly,
                                         float s, float c, float cx0, float cy0,
                                         unsigned& idx, float& dx, float& dy) {
    float yf = (float)((oct_beg + tb) << 3) + fly;
    float x_in = fmaf(s, yf, cx0);
    float y_in = fmaf(c, yf, cy0);
    int ix = (int)x_in;                 // positive -> trunc == floor
    int iy = (int)y_in;
    dx = x_in - (float)ix;
    dy = y_in - (float)iy;
    idx = __umul24((unsigned)iy, PWS) + (unsigned)ix;
}

// Wave = (angle, 8-wide x-strip, y-chunk); lane = (ly=lane>>3, lx=lane&7).
// Interior loop 4-way unrolled (4 independent gather chains, 4 accumulators)
// to raise per-wave MLP; edge loop exact wrap+bounds.
__global__ __launch_bounds__(256) void k_proj6(const unsigned int* __restrict__ RP,
                                               const float2* __restrict__ cs,
                                               float* __restrict__ partial) {
    int wave_id = blockIdx.x * 4 + (threadIdx.x >> 6);
    int lane = threadIdx.x & 63;
    int lx = lane & 7;
    int ly = lane >> 3;

    int xs = wave_id % XS_N;
    int t  = wave_id / XS_N;
    int a  = t & (NA - 1);
    int chunk = t >> 6;

    int X0 = xs * 8;
    int X = X0 + lx;

    float2 sc = cs[a];
    float c = sc.x;
    float s = sc.y;
    float bx = -CENTER * (c + s - 1.0f);
    float by = -CENTER * (c - s - 1.0f);
    float cx0 = fmaf(c, (float)X, bx);      // x_in = cx0 + s*Y  (unshifted)
    float cy0 = fmaf(-s, (float)X, by);     // y_in = cy0 + c*Y
    float cxs = cx0 + (float)PW;            // shifted (edge path)
    float cys = cy0 + (float)PW;

    int oct_beg = (chunk * XS_N) / YS;
    int oct_end = ((chunk + 1) * XS_N) / YS;
    int noct = oct_end - oct_beg;

    // ---- per-oct classification (lane l <-> oct_beg+l), proven r4-r8 ----
    float ab = fabsf(c) + fabsf(s);
    float E = fmaf(3.5f, ab, 2.0f);
    float D = 3.5f * ab;
    float xcw = fmaf(c, (float)X0 + 3.5f, bx);
    float ycw = fmaf(-s, (float)X0 + 3.5f, by);
    float ycen = (float)((oct_beg + lane) * 8) + 3.5f;
    float xcf = fmaf(s, ycen, xcw);
    float ycf = fmaf(c, ycen, ycw);
    float uxf = xcf - 211.0f + E + 1449.0f;
    float uyf = ycf - 211.0f + E + 1449.0f;
    unsigned iux = (unsigned)uxf;
    unsigned iuy = (unsigned)uyf;
    unsigned mxr = iux - __umul24(__umul24(iux, 11581u) >> 24, 1449u);
    unsigned myr = iuy - __umul24(__umul24(iuy, 11581u) >> 24, 1449u);
    unsigned lim = (unsigned)(1026.0f + 2.0f * E);
    bool act = (lane < noct) && (mxr <= lim) && (myr <= lim);
    bool interior = (xcf - D >= 213.0f) && (xcf + D <= 1234.0f) &&
                    (ycf - D >= 213.0f) && (ycf + D <= 1234.0f);
    unsigned long long mask_int  = __ballot(act && interior);
    unsigned long long mask_edge = __ballot(act && !interior);

    float fly = (float)ly;
    float acc0 = 0.0f, acc1 = 0.0f, acc2 = 0.0f, acc3 = 0.0f;

    // ---- interior fast path: 4-way MLP unroll ----
    while (mask_int) {
        int tb0 = (int)__builtin_ctzll(mask_int); mask_int &= mask_int - 1;
        int tb1 = tb0, tb2 = tb0, tb3 = tb0;
        int cnt = 1;
        if (mask_int) {
            tb1 = (int)__builtin_ctzll(mask_int); mask_int &= mask_int - 1; cnt = 2;
            if (mask_int) {
                tb2 = (int)__builtin_ctzll(mask_int); mask_int &= mask_int - 1; cnt = 3;
                if (mask_int) {
                    tb3 = (int)__builtin_ctzll(mask_int); mask_int &= mask_int - 1; cnt = 4;
                }
            }
        }
        unsigned i0, i1, i2, i3;
        float dx0, dy0, dx1, dy1, dx2, dy2, dx3, dy3;
        addr_int(tb0, oct_beg, fly, s, c, cx0, cy0, i0, dx0, dy0);
        addr_int(tb1, oct_beg, fly, s, c, cx0, cy0, i1, dx1, dy1);
        addr_int(tb2, oct_beg, fly, s, c, cx0, cy0, i2, dx2, dy2);
        addr_int(tb3, oct_beg, fly, s, c, cx0, cy0, i3, dx3, dy3);
        uint2 q0 = *reinterpret_cast<const uint2*>(RP + i0);
        uint2 q1 = *reinterpret_cast<const uint2*>(RP + i1);
        uint2 q2 = *reinterpret_cast<const uint2*>(RP + i2);
        uint2 q3 = *reinterpret_cast<const uint2*>(RP + i3);
        acc0 = blend4(q0, dx0, dy0, acc0);
        if (cnt > 1) acc1 = blend4(q1, dx1, dy1, acc1);
        if (cnt > 2) acc2 = blend4(q2, dx2, dy2, acc2);
        if (cnt > 3) acc3 = blend4(q3, dx3, dy3, acc3);
    }

    // ---- edge path: exact wrap + bounds (loads always in-buffer) ----
    while (mask_edge) {
        int tb = (int)__builtin_ctzll(mask_edge);
        mask_edge &= mask_edge - 1;
        float yf = (float)((oct_beg + tb) << 3) + fly;
        float x_s = fmaf(s, yf, cxs);
        float y_s = fmaf(c, yf, cys);
        int ixs = (int)x_s;                 // positive (>=424) -> trunc == floor
        int iys = (int)y_s;
        float dx = x_s - (float)ixs;
        float dy = y_s - (float)iys;
        unsigned vx = (unsigned)ixs;        // [424, 3922) — mul24-safe
        unsigned vy = (unsigned)iys;
        unsigned x0 = vx - __umul24(__umul24(vx, 11581u) >> 24, 1449u);
        unsigned y0 = vy - __umul24(__umul24(vy, 11581u) >> 24, 1449u);
        bool ok = ((x0 - (PAD0 - 1)) <= 1024u) && ((y0 - (PAD0 - 1)) <= 1024u);
        unsigned idx = __umul24(y0, PWS) + x0;
        uint2 q = *reinterpret_cast<const uint2*>(RP + idx);
        float contrib = blend4_val(q, dx, dy);
        acc0 += ok ? contrib : 0.0f;
    }

    float acc = (acc0 + acc1) + (acc2 + acc3);
    acc += __shfl_xor(acc, 8, 64);
    acc += __shfl_xor(acc, 16, 64);
    acc += __shfl_xor(acc, 32, 64);

    if (ly == 0) partial[(size_t)chunk * NOUT + a * OW + X] = acc;
}

// ---------- round-5 proven fallback (fp32 P, float2 taps) ----------
__global__ __launch_bounds__(256) void k_pad_dwt(const float* __restrict__ img,
                                                 float* __restrict__ P) {
    int gid = blockIdx.x * blockDim.x + threadIdx.x;
    if (gid >= PW * PW) return;
    int r = gid / PW;
    int cidx = gid - r * PW;
    P[gid] = conv_at(img, r, cidx);
}

__global__ __launch_bounds__(256) void k_proj3(const float* __restrict__ P,
                                               float* __restrict__ partial) {
    int wave_id = blockIdx.x * 4 + (threadIdx.x >> 6);
    int lane = threadIdx.x & 63;
    int lx = lane & 7;
    int ly = lane >> 3;

    int xs = wave_id % XS_N;
    int t  = wave_id / XS_N;
    int a  = t & (NA - 1);
    int chunk = t >> 6;

    int X0 = xs * 8;
    int X = X0 + lx;

    float fa = (float)a;
    float c = cosf(fa);
    float s = sinf(fa);
    float bx = -CENTER * (c + s - 1.0f);
    float by = -CENTER * (c - s - 1.0f);
    float cxs = fmaf(c, (float)X, bx) + (float)PW;
    float cys = fmaf(-s, (float)X, by) + (float)PW;

    int oct_beg = (chunk * XS_N) / YS;
    int oct_end = ((chunk + 1) * XS_N) / YS;
    int noct = oct_end - oct_beg;

    float E = fmaf(3.5f, fabsf(c) + fabsf(s), 2.0f);
    float xcw = fmaf(c, (float)X0 + 3.5f, bx);
    float ycw = fmaf(-s, (float)X0 + 3.5f, by);
    float ycen = (float)((oct_beg + lane) * 8) + 3.5f;
    float uxf = fmaf(s, ycen, xcw) - 211.0f + E + 1449.0f;
    float uyf = fmaf(c, ycen, ycw) - 211.0f + E + 1449.0f;
    unsigned iux = (unsigned)uxf;
    unsigned iuy = (unsigned)uyf;
    unsigned mxr = iux - ((iux * 11581u) >> 24) * 1449u;
    unsigned myr = iuy - ((iuy * 11581u) >> 24) * 1449u;
    unsigned lim = (unsigned)(1026.0f + 2.0f * E);
    bool act = (lane < noct) && (mxr <= lim) && (myr <= lim);
    unsigned long long mask = __ballot(act);

    float acc = 0.0f;
    while (mask) {
        int tb = (int)__builtin_ctzll(mask);
        mask &= mask - 1;
        float yf = (float)(((oct_beg + tb) << 3) + ly);
        float x_s = fmaf(s, yf, cxs);
        float y_s = fmaf(c, yf, cys);
        float fx = floorf(x_s);
        float fy = floorf(y_s);
        float dx = x_s - fx;
        float dy = y_s - fy;
        unsigned vx = (unsigned)fx;
        unsigned vy = (unsigned)fy;
        int x0 = (int)(vx - ((vx * 11581u) >> 24) * 1449u);
        int y0 = (int)(vy - ((vy * 11581u) >> 24) * 1449u);
        bool ok = ((unsigned)(x0 - (PAD0 - 1)) <= 1024u) &&
                  ((unsigned)(y0 - (PAD0 - 1)) <= 1024u);
        const float* p0 = P + (y0 * PW + x0);
        float2 tv = *reinterpret_cast<const float2*>(p0);
        float2 bv = *reinterpret_cast<const float2*>(p0 + PW);
        float top = fmaf(dx, tv.y - tv.x, tv.x);
        float bot = fmaf(dx, bv.y - bv.x, bv.x);
        float contrib = fmaf(dy, bot - top, top);
        acc += ok ? contrib : 0.0f;
    }

    acc += __shfl_xor(acc, 8, 64);
    acc += __shfl_xor(acc, 16, 64);
    acc += __shfl_xor(acc, 32, 64);

    if (ly == 0) partial[(size_t)chunk * NOUT + a * OW + X] = acc;
}

// ---------- shared epilogue ----------
template <int NCH>
__global__ __launch_bounds__(256) void k_combine(const float* __restrict__ partial,
                                                 float* __restrict__ out) {
    int gid = blockIdx.x * blockDim.x + threadIdx.x;
    if (gid >= NOUT) return;
    float sum = 0.0f;
#pragma unroll
    for (int cth = 0; cth < NCH; ++cth) sum += partial[(size_t)cth * NOUT + gid];
    int a = gid / OW;
    int x = gid % OW;
    out[x * NA + a] = sum;   // transpose: A = lines.T
}

__global__ __launch_bounds__(256) void k_max1(const float* __restrict__ out,
                                              float* __restrict__ bmax) {
    __shared__ float sm[4];
    const float4* o4 = reinterpret_cast<const float4*>(out);
    const int n4 = NOUT / 4;
    float m = -3.4e38f;
    for (int i = blockIdx.x * 256 + threadIdx.x; i < n4; i += gridDim.x * 256) {
        float4 v = o4[i];
        m = fmaxf(fmaxf(fmaxf(m, v.x), fmaxf(v.y, v.z)), v.w);
    }
#pragma unroll
    for (int off = 32; off > 0; off >>= 1) m = fmaxf(m, __shfl_down(m, off, 64));
    int lane = threadIdx.x & 63;
    int w = threadIdx.x >> 6;
    if (lane == 0) sm[w] = m;
    __syncthreads();
    if (threadIdx.x == 0)
        bmax[blockIdx.x] = fmaxf(fmaxf(sm[0], sm[1]), fmaxf(sm[2], sm[3]));
}

__global__ __launch_bounds__(64) void k_max2(const float* __restrict__ bmax,
                                             float* __restrict__ mx) {
    float m = bmax[threadIdx.x];
#pragma unroll
    for (int off = 32; off > 0; off >>= 1) m = fmaxf(m, __shfl_down(m, off, 64));
    if (threadIdx.x == 0) *mx = m;
}

__global__ __launch_bounds__(256) void k_norm(float* __restrict__ out,
                                              const float* __restrict__ mx) {
    int gid = blockIdx.x * blockDim.x + threadIdx.x;
    if (gid < NOUT) out[gid] = out[gid] / (*mx);
}

extern "C" void kernel_launch(void* const* d_in, const int* in_sizes, int n_in,
                              void* d_out, int out_size, void* d_ws, size_t ws_size,
                              hipStream_t stream) {
    const float* img = (const float*)d_in[0];
    float* out = (float*)d_out;

    const size_t need_new = (NRP + 16) * 4 + ((size_t)YS * NOUT + 65 + 128) * 4;
    const size_t np_alloc = NPAD + PW + 8;
    const size_t need_old = np_alloc * 4 + ((size_t)YS * NOUT + 65) * 4;

    if (ws_size >= need_new) {
        unsigned int* RP = (unsigned int*)d_ws;
        float* partial = (float*)(RP + NRP + 16);
        float* bmax = partial + (size_t)YS * NOUT;
        float* mx = bmax + 64;
        float2* cs = (float2*)(mx + 1);      // 64 float2
        k_trig<<<1, 64, 0, stream>>>(cs);
        k_pack<<<(int)((NRP + 255) / 256), 256, 0, stream>>>(img, RP);
        k_proj6<<<NBLOCKS, 256, 0, stream>>>(RP, cs, partial);
        k_combine<YS><<<(NOUT + 255) / 256, 256, 0, stream>>>(partial, out);
        k_max1<<<64, 256, 0, stream>>>(out, bmax);
        k_max2<<<1, 64, 0, stream>>>(bmax, mx);
        k_norm<<<(NOUT + 255) / 256, 256, 0, stream>>>(out, mx);
    } else if (ws_size >= need_old) {
        float* P = (float*)d_ws;
        float* partial = P + np_alloc;
        float* bmax = partial + (size_t)YS * NOUT;
        float* mx = bmax + 64;
        k_pad_dwt<<<(int)((NPAD + 255) / 256), 256, 0, stream>>>(img, P);
        k_proj3<<<NBLOCKS, 256, 0, stream>>>(P, partial);
        k_combine<YS><<<(NOUT + 255) / 256, 256, 0, stream>>>(partial, out);
        k_max1<<<64, 256, 0, stream>>>(out, bmax);
        k_max2<<<1, 64, 0, stream>>>(bmax, mx);
        k_norm<<<(NOUT + 255) / 256, 256, 0, stream>>>(out, mx);
    }
}

// Round 10
// 94.356 us; speedup vs baseline: 1.0435x; 1.0435x over previous
//
#include <hip/hip_runtime.h>
#include <hip/hip_bf16.h>
#include <hip/hip_fp16.h>

// Geometry (compile-time):
//  image 2048x2048 f32 -> conv2x2 stride2 -> hi 1024x1024
//  padded 1449x1449, hi at offset (212,212), center=724
//  out grid 1448x1448, 64 angles (theta = 0..63 radians)
//  A[x][a] = sum_y bilinear_wrap(padded, rot(x,y,a)) ; out = A / max(A)

#define HM 1024
#define PW 1449
#define PWS 1450           // RP row stride (col 1449 duplicates col 0 for x-wrap)
#define PAD0 212
#define OW 1448
#define NA 64
#define NOUT (OW * NA)     // 92672 = 362*256
#define CENTER 724.0f
#define XS_N 181           // 1448/8 x-strips
#define YS 4               // y chunks
#define NWAVES (XS_N * NA * YS)   // 46336
#define NBLOCKS (NWAVES / 4)      // 11584
#define NRP ((size_t)PW * PWS)    // 2,101,050 packed elements
#define NPAD ((size_t)PW * PW)
#define NQ 363                    // 4-row pack strips

#ifndef __has_builtin
#define __has_builtin(x) 0
#endif
#if __has_builtin(__builtin_amdgcn_fdot2) && __has_builtin(__builtin_amdgcn_cvt_pkrtz)
#define USE_DOT2 1
typedef _Float16 h2 __attribute__((ext_vector_type(2)));   // fdot2 operand type
__device__ __forceinline__ h2 pkrtz(float a, float b) {
    return __builtin_bit_cast(h2, __builtin_amdgcn_cvt_pkrtz(a, b));
}
#else
#define USE_DOT2 0
#endif

// conv value of padded image at (r,c); 0 outside data square
__device__ __forceinline__ float conv_at(const float* __restrict__ img, int r, int c) {
    int i = r - PAD0;
    int j = c - PAD0;
    if ((unsigned)i >= (unsigned)HM || (unsigned)j >= (unsigned)HM) return 0.0f;
    const float2* r0 = reinterpret_cast<const float2*>(img + (size_t)(2 * i) * 2048);
    const float2* r1 = reinterpret_cast<const float2*>(img + (size_t)(2 * i + 1) * 2048);
    float2 a = r0[j];
    float2 b = r1[j];
    return fmaf(-0.1384f, a.x,
           fmaf( 0.7243f, a.y,
           fmaf(-0.6038f, b.x, 0.1601f * b.y)));
}

// 64-entry cos/sin table (bit-identical to device cosf/sinf used before)
__global__ __launch_bounds__(64) void k_trig(float2* __restrict__ cs) {
    int i = threadIdx.x;
    cs[i] = make_float2(cosf((float)i), sinf((float)i));
}

// RP[r*PWS+x] = half2( P[r][x'], P[(r+1)%1449][x'] ), x' = x%1449.
// 4-tall strips: 5 conv evals produce 4 packed outputs (amortize shared rows).
__global__ __launch_bounds__(256) void k_pack4(const float* __restrict__ img,
                                               unsigned int* __restrict__ RP) {
    int gid = blockIdx.x * blockDim.x + threadIdx.x;
    if (gid >= NQ * PWS) return;
    int rq = gid / PWS;
    int c = gid - rq * PWS;
    int cx = (c == PW) ? 0 : c;
    int r0 = rq * 4;
    int nr = (PW - r0 < 4) ? (PW - r0) : 4;   // rows in this strip (last strip: 1)
    float v[5];
#pragma unroll
    for (int k = 0; k <= 4; ++k) {
        if (k <= nr) {
            int row = r0 + k;
            if (row == PW) row = 0;
            v[k] = conv_at(img, row, cx);
        }
    }
#pragma unroll
    for (int k = 0; k < 4; ++k) {
        if (k < nr) {
            __half2 h = __floats2half2_rn(v[k], v[k + 1]);  // low = row, high = row+1
            RP[(size_t)(r0 + k) * PWS + c] = *reinterpret_cast<unsigned int*>(&h);
        }
    }
}

// 4-tap bilinear blend from one packed uint2. q.x=(v00,v10), q.y=(v01,v11).
__device__ __forceinline__ float blend4(uint2 q, float dx, float dy, float acc) {
#if USE_DOT2
    float omdx = 1.0f - dx;
    float omdy = 1.0f - dy;
    h2 w0 = pkrtz(omdy * omdx, dy * omdx);   // (w00, w10)
    h2 w1 = pkrtz(omdy * dx,   dy * dx);     // (w01, w11)
    acc = __builtin_amdgcn_fdot2(__builtin_bit_cast(h2, q.x), w0, acc, false);
    acc = __builtin_amdgcn_fdot2(__builtin_bit_cast(h2, q.y), w1, acc, false);
    return acc;
#else
    float2 f0 = __half22float2(*reinterpret_cast<const __half2*>(&q.x));
    float2 f1 = __half22float2(*reinterpret_cast<const __half2*>(&q.y));
    float top = fmaf(dx, f1.x - f0.x, f0.x);
    float bot = fmaf(dx, f1.y - f0.y, f0.y);
    return fmaf(dy, bot - top, acc + top);
#endif
}

__device__ __forceinline__ float blend4_val(uint2 q, float dx, float dy) {
#if USE_DOT2
    float omdx = 1.0f - dx;
    float omdy = 1.0f - dy;
    h2 w0 = pkrtz(omdy * omdx, dy * omdx);
    h2 w1 = pkrtz(omdy * dx,   dy * dx);
    float t = __builtin_amdgcn_fdot2(__builtin_bit_cast(h2, q.x), w0, 0.0f, false);
    return __builtin_amdgcn_fdot2(__builtin_bit_cast(h2, q.y), w1, t, false);
#else
    float2 f0 = __half22float2(*reinterpret_cast<const __half2*>(&q.x));
    float2 f1 = __half22float2(*reinterpret_cast<const __half2*>(&q.y));
    float top = fmaf(dx, f1.x - f0.x, f0.x);
    float bot = fmaf(dx, f1.y - f0.y, f0.y);
    return fmaf(dy, bot - top, top);
#endif
}

// Wave = (angle, 8-wide x-strip, y-chunk); lane = (ly=lane>>3, lx=lane&7).
// PROVEN round-8 body (79 us), only change: trig from table.
__global__ __launch_bounds__(256) void k_proj5t(const unsigned int* __restrict__ RP,
                                                const float2* __restrict__ cs,
                                                float* __restrict__ partial) {
    int wave_id = blockIdx.x * 4 + (threadIdx.x >> 6);
    int lane = threadIdx.x & 63;
    int lx = lane & 7;
    int ly = lane >> 3;

    int xs = wave_id % XS_N;
    int t  = wave_id / XS_N;
    int a  = t & (NA - 1);
    int chunk = t >> 6;

    int X0 = xs * 8;
    int X = X0 + lx;

    float2 sc = cs[a];
    float c = sc.x;
    float s = sc.y;
    float bx = -CENTER * (c + s - 1.0f);
    float by = -CENTER * (c - s - 1.0f);
    float cx0 = fmaf(c, (float)X, bx);      // x_in = cx0 + s*Y  (unshifted)
    float cy0 = fmaf(-s, (float)X, by);     // y_in = cy0 + c*Y
    float cxs = cx0 + (float)PW;            // shifted (edge path)
    float cys = cy0 + (float)PW;

    int oct_beg = (chunk * XS_N) / YS;
    int oct_end = ((chunk + 1) * XS_N) / YS;
    int noct = oct_end - oct_beg;

    // ---- per-oct classification (lane l <-> oct_beg+l), proven r4-r8 ----
    float ab = fabsf(c) + fabsf(s);
    float E = fmaf(3.5f, ab, 2.0f);
    float D = 3.5f * ab;
    float xcw = fmaf(c, (float)X0 + 3.5f, bx);
    float ycw = fmaf(-s, (float)X0 + 3.5f, by);
    float ycen = (float)((oct_beg + lane) * 8) + 3.5f;
    float xcf = fmaf(s, ycen, xcw);
    float ycf = fmaf(c, ycen, ycw);
    float uxf = xcf - 211.0f + E + 1449.0f;
    float uyf = ycf - 211.0f + E + 1449.0f;
    unsigned iux = (unsigned)uxf;
    unsigned iuy = (unsigned)uyf;
    unsigned mxr = iux - __umul24(__umul24(iux, 11581u) >> 24, 1449u);
    unsigned myr = iuy - __umul24(__umul24(iuy, 11581u) >> 24, 1449u);
    unsigned lim = (unsigned)(1026.0f + 2.0f * E);
    bool act = (lane < noct) && (mxr <= lim) && (myr <= lim);
    bool interior = (xcf - D >= 213.0f) && (xcf + D <= 1234.0f) &&
                    (ycf - D >= 213.0f) && (ycf + D <= 1234.0f);
    unsigned long long mask_int  = __ballot(act && interior);
    unsigned long long mask_edge = __ballot(act && !interior);

    float fly = (float)ly;
    float acc = 0.0f;

    // ---- interior fast path: no mod, no bounds, trunc=floor ----
    while (mask_int) {
        int tb = (int)__builtin_ctzll(mask_int);
        mask_int &= mask_int - 1;
        float yb = (float)((oct_beg + tb) << 3);
        float yf = yb + fly;
        float x_in = fmaf(s, yf, cx0);
        float y_in = fmaf(c, yf, cy0);
        int ix = (int)x_in;                 // positive -> trunc == floor
        int iy = (int)y_in;
        float dx = x_in - (float)ix;
        float dy = y_in - (float)iy;
        unsigned idx = __umul24((unsigned)iy, PWS) + (unsigned)ix;
        uint2 q = *reinterpret_cast<const uint2*>(RP + idx);
        acc = blend4(q, dx, dy, acc);
    }

    // ---- edge path: exact wrap + bounds (loads always in-buffer) ----
    while (mask_edge) {
        int tb = (int)__builtin_ctzll(mask_edge);
        mask_edge &= mask_edge - 1;
        float yb = (float)((oct_beg + tb) << 3);
        float yf = yb + fly;
        float x_s = fmaf(s, yf, cxs);
        float y_s = fmaf(c, yf, cys);
        int ixs = (int)x_s;                 // positive (>=424) -> trunc == floor
        int iys = (int)y_s;
        float dx = x_s - (float)ixs;
        float dy = y_s - (float)iys;
        unsigned vx = (unsigned)ixs;        // [424, 3922) — mul24-safe
        unsigned vy = (unsigned)iys;
        unsigned x0 = vx - __umul24(__umul24(vx, 11581u) >> 24, 1449u);
        unsigned y0 = vy - __umul24(__umul24(vy, 11581u) >> 24, 1449u);
        bool ok = ((x0 - (PAD0 - 1)) <= 1024u) && ((y0 - (PAD0 - 1)) <= 1024u);
        unsigned idx = __umul24(y0, PWS) + x0;
        uint2 q = *reinterpret_cast<const uint2*>(RP + idx);
        float contrib = blend4_val(q, dx, dy);
        acc += ok ? contrib : 0.0f;
    }

    acc += __shfl_xor(acc, 8, 64);
    acc += __shfl_xor(acc, 16, 64);
    acc += __shfl_xor(acc, 32, 64);

    if (ly == 0) partial[(size_t)chunk * NOUT + a * OW + X] = acc;
}

// ---------- fused combine + transpose-write + per-block max ----------
// NOUT = 362*256 exactly: grid 362, no OOB threads.
__global__ __launch_bounds__(256) void k_combmax(const float* __restrict__ partial,
                                                 float* __restrict__ out,
                                                 float* __restrict__ bmax) {
    __shared__ float sm[4];
    int gid = blockIdx.x * 256 + threadIdx.x;
    float sum = 0.0f;
#pragma unroll
    for (int cth = 0; cth < YS; ++cth) sum += partial[(size_t)cth * NOUT + gid];
    int a = gid / OW;
    int x = gid - a * OW;
    out[x * NA + a] = sum;   // transpose: A = lines.T
    float m = sum;
#pragma unroll
    for (int off = 32; off > 0; off >>= 1) m = fmaxf(m, __shfl_down(m, off, 64));
    int lane = threadIdx.x & 63;
    int w = threadIdx.x >> 6;
    if (lane == 0) sm[w] = m;
    __syncthreads();
    if (threadIdx.x == 0)
        bmax[blockIdx.x] = fmaxf(fmaxf(sm[0], sm[1]), fmaxf(sm[2], sm[3]));
}

__global__ __launch_bounds__(256) void k_max2(const float* __restrict__ bmax,
                                              float* __restrict__ mx) {
    __shared__ float sm[4];
    float m = -3.4e38f;
    for (int i = threadIdx.x; i < 362; i += 256) m = fmaxf(m, bmax[i]);
#pragma unroll
    for (int off = 32; off > 0; off >>= 1) m = fmaxf(m, __shfl_down(m, off, 64));
    int lane = threadIdx.x & 63;
    int w = threadIdx.x >> 6;
    if (lane == 0) sm[w] = m;
    __syncthreads();
    if (threadIdx.x == 0)
        *mx = fmaxf(fmaxf(sm[0], sm[1]), fmaxf(sm[2], sm[3]));
}

__global__ __launch_bounds__(256) void k_norm(float* __restrict__ out,
                                              const float* __restrict__ mx) {
    int gid = blockIdx.x * blockDim.x + threadIdx.x;
    if (gid < NOUT) out[gid] = out[gid] / (*mx);
}

// ---------- round-5 proven fallback (fp32 P, float2 taps) ----------
__global__ __launch_bounds__(256) void k_pad_dwt(const float* __restrict__ img,
                                                 float* __restrict__ P) {
    int gid = blockIdx.x * blockDim.x + threadIdx.x;
    if (gid >= PW * PW) return;
    int r = gid / PW;
    int cidx = gid - r * PW;
    P[gid] = conv_at(img, r, cidx);
}

__global__ __launch_bounds__(256) void k_proj3(const float* __restrict__ P,
                                               float* __restrict__ partial) {
    int wave_id = blockIdx.x * 4 + (threadIdx.x >> 6);
    int lane = threadIdx.x & 63;
    int lx = lane & 7;
    int ly = lane >> 3;

    int xs = wave_id % XS_N;
    int t  = wave_id / XS_N;
    int a  = t & (NA - 1);
    int chunk = t >> 6;

    int X0 = xs * 8;
    int X = X0 + lx;

    float fa = (float)a;
    float c = cosf(fa);
    float s = sinf(fa);
    float bx = -CENTER * (c + s - 1.0f);
    float by = -CENTER * (c - s - 1.0f);
    float cxs = fmaf(c, (float)X, bx) + (float)PW;
    float cys = fmaf(-s, (float)X, by) + (float)PW;

    int oct_beg = (chunk * XS_N) / YS;
    int oct_end = ((chunk + 1) * XS_N) / YS;
    int noct = oct_end - oct_beg;

    float E = fmaf(3.5f, fabsf(c) + fabsf(s), 2.0f);
    float xcw = fmaf(c, (float)X0 + 3.5f, bx);
    float ycw = fmaf(-s, (float)X0 + 3.5f, by);
    float ycen = (float)((oct_beg + lane) * 8) + 3.5f;
    float uxf = fmaf(s, ycen, xcw) - 211.0f + E + 1449.0f;
    float uyf = fmaf(c, ycen, ycw) - 211.0f + E + 1449.0f;
    unsigned iux = (unsigned)uxf;
    unsigned iuy = (unsigned)uyf;
    unsigned mxr = iux - ((iux * 11581u) >> 24) * 1449u;
    unsigned myr = iuy - ((iuy * 11581u) >> 24) * 1449u;
    unsigned lim = (unsigned)(1026.0f + 2.0f * E);
    bool act = (lane < noct) && (mxr <= lim) && (myr <= lim);
    unsigned long long mask = __ballot(act);

    float acc = 0.0f;
    while (mask) {
        int tb = (int)__builtin_ctzll(mask);
        mask &= mask - 1;
        float yf = (float)(((oct_beg + tb) << 3) + ly);
        float x_s = fmaf(s, yf, cxs);
        float y_s = fmaf(c, yf, cys);
        float fx = floorf(x_s);
        float fy = floorf(y_s);
        float dx = x_s - fx;
        float dy = y_s - fy;
        unsigned vx = (unsigned)fx;
        unsigned vy = (unsigned)fy;
        int x0 = (int)(vx - ((vx * 11581u) >> 24) * 1449u);
        int y0 = (int)(vy - ((vy * 11581u) >> 24) * 1449u);
        bool ok = ((unsigned)(x0 - (PAD0 - 1)) <= 1024u) &&
                  ((unsigned)(y0 - (PAD0 - 1)) <= 1024u);
        const float* p0 = P + (y0 * PW + x0);
        float2 tv = *reinterpret_cast<const float2*>(p0);
        float2 bv = *reinterpret_cast<const float2*>(p0 + PW);
        float top = fmaf(dx, tv.y - tv.x, tv.x);
        float bot = fmaf(dx, bv.y - bv.x, bv.x);
        float contrib = fmaf(dy, bot - top, top);
        acc += ok ? contrib : 0.0f;
    }

    acc += __shfl_xor(acc, 8, 64);
    acc += __shfl_xor(acc, 16, 64);
    acc += __shfl_xor(acc, 32, 64);

    if (ly == 0) partial[(size_t)chunk * NOUT + a * OW + X] = acc;
}

extern "C" void kernel_launch(void* const* d_in, const int* in_sizes, int n_in,
                              void* d_out, int out_size, void* d_ws, size_t ws_size,
                              hipStream_t stream) {
    const float* img = (const float*)d_in[0];
    float* out = (float*)d_out;

    const size_t need_new = (NRP + 16) * 4 + ((size_t)YS * NOUT + 512 + 1 + 128) * 4;
    const size_t np_alloc = NPAD + PW + 8;
    const size_t need_old = np_alloc * 4 + ((size_t)YS * NOUT + 512 + 1) * 4;

    if (ws_size >= need_new) {
        unsigned int* RP = (unsigned int*)d_ws;
        float* partial = (float*)(RP + NRP + 16);
        float* bmax = partial + (size_t)YS * NOUT;   // 512 slots
        float* mx = bmax + 512;
        float2* cs = (float2*)(mx + 1);              // 64 float2
        k_trig<<<1, 64, 0, stream>>>(cs);
        k_pack4<<<(NQ * PWS + 255) / 256, 256, 0, stream>>>(img, RP);
        k_proj5t<<<NBLOCKS, 256, 0, stream>>>(RP, cs, partial);
        k_combmax<<<NOUT / 256, 256, 0, stream>>>(partial, out, bmax);
        k_max2<<<1, 256, 0, stream>>>(bmax, mx);
        k_norm<<<(NOUT + 255) / 256, 256, 0, stream>>>(out, mx);
    } else if (ws_size >= need_old) {
        float* P = (float*)d_ws;
        float* partial = P + np_alloc;
        float* bmax = partial + (size_t)YS * NOUT;
        float* mx = bmax + 512;
        k_pad_dwt<<<(int)((NPAD + 255) / 256), 256, 0, stream>>>(img, P);
        k_proj3<<<NBLOCKS, 256, 0, stream>>>(P, partial);
        k_combmax<<<NOUT / 256, 256, 0, stream>>>(partial, out, bmax);
        k_max2<<<1, 256, 0, stream>>>(bmax, mx);
        k_norm<<<(NOUT + 255) / 256, 256, 0, stream>>>(out, mx);
    }
}

// Round 11
// 88.224 us; speedup vs baseline: 1.1160x; 1.0695x over previous
//
#include <hip/hip_runtime.h>
#include <hip/hip_bf16.h>
#include <hip/hip_fp16.h>

// Geometry (compile-time):
//  image 2048x2048 f32 -> conv2x2 stride2 -> hi 1024x1024
//  padded 1449x1449, hi at offset (212,212), center=724
//  out grid 1448x1448, 64 angles (theta = 0..63 radians)
//  A[x][a] = sum_y bilinear_wrap(padded, rot(x,y,a)) ; out = A / max(A)

#define HM 1024
#define PW 1449
#define PWS 1450           // RP row stride (col 1449 duplicates col 0 for x-wrap)
#define PAD0 212
#define OW 1448
#define NA 64
#define NOUT (OW * NA)     // 92672 = 362*256
#define CENTER 724.0f
#define XS_N 181           // 1448/8 x-strips
#define YS 4               // y chunks
#define NWAVES (XS_N * NA * YS)   // 46336
#define NBLOCKS (NWAVES / 4)      // 11584
#define NRP ((size_t)PW * PWS)    // 2,101,050 packed elements
#define NPAD ((size_t)PW * PW)

#ifndef __has_builtin
#define __has_builtin(x) 0
#endif
#if __has_builtin(__builtin_amdgcn_fdot2) && __has_builtin(__builtin_amdgcn_cvt_pkrtz)
#define USE_DOT2 1
typedef _Float16 h2 __attribute__((ext_vector_type(2)));   // fdot2 operand type
__device__ __forceinline__ h2 pkrtz(float a, float b) {
    return __builtin_bit_cast(h2, __builtin_amdgcn_cvt_pkrtz(a, b));
}
#else
#define USE_DOT2 0
#endif

// conv value of padded image at (r,c); 0 outside data square
__device__ __forceinline__ float conv_at(const float* __restrict__ img, int r, int c) {
    int i = r - PAD0;
    int j = c - PAD0;
    if ((unsigned)i >= (unsigned)HM || (unsigned)j >= (unsigned)HM) return 0.0f;
    const float2* r0 = reinterpret_cast<const float2*>(img + (size_t)(2 * i) * 2048);
    const float2* r1 = reinterpret_cast<const float2*>(img + (size_t)(2 * i + 1) * 2048);
    float2 a = r0[j];
    float2 b = r1[j];
    return fmaf(-0.1384f, a.x,
           fmaf( 0.7243f, a.y,
           fmaf(-0.6038f, b.x, 0.1601f * b.y)));
}

// ROUND-8 PROVEN pack: RP[r*PWS+x] = half2( P[r][x'], P[(r+1)%1449][x'] ).
__global__ __launch_bounds__(256) void k_pack(const float* __restrict__ img,
                                              unsigned int* __restrict__ RP) {
    int gid = blockIdx.x * blockDim.x + threadIdx.x;
    if (gid >= (int)NRP) return;
    int r = gid / PWS;
    int x = gid - r * PWS;
    int cx = (x == PW) ? 0 : x;
    int r1 = (r == PW - 1) ? 0 : r + 1;
    float v0 = conv_at(img, r, cx);
    float v1 = conv_at(img, r1, cx);
    __half2 h = __floats2half2_rn(v0, v1);   // low = row r, high = row r+1
    RP[gid] = *reinterpret_cast<unsigned int*>(&h);
}

// 4-tap bilinear blend from one packed uint2. q.x=(v00,v10), q.y=(v01,v11).
__device__ __forceinline__ float blend4(uint2 q, float dx, float dy, float acc) {
#if USE_DOT2
    float omdx = 1.0f - dx;
    float omdy = 1.0f - dy;
    h2 w0 = pkrtz(omdy * omdx, dy * omdx);   // (w00, w10)
    h2 w1 = pkrtz(omdy * dx,   dy * dx);     // (w01, w11)
    acc = __builtin_amdgcn_fdot2(__builtin_bit_cast(h2, q.x), w0, acc, false);
    acc = __builtin_amdgcn_fdot2(__builtin_bit_cast(h2, q.y), w1, acc, false);
    return acc;
#else
    float2 f0 = __half22float2(*reinterpret_cast<const __half2*>(&q.x));
    float2 f1 = __half22float2(*reinterpret_cast<const __half2*>(&q.y));
    float top = fmaf(dx, f1.x - f0.x, f0.x);
    float bot = fmaf(dx, f1.y - f0.y, f0.y);
    return fmaf(dy, bot - top, acc + top);
#endif
}

__device__ __forceinline__ float blend4_val(uint2 q, float dx, float dy) {
#if USE_DOT2
    float omdx = 1.0f - dx;
    float omdy = 1.0f - dy;
    h2 w0 = pkrtz(omdy * omdx, dy * omdx);
    h2 w1 = pkrtz(omdy * dx,   dy * dx);
    float t = __builtin_amdgcn_fdot2(__builtin_bit_cast(h2, q.x), w0, 0.0f, false);
    return __builtin_amdgcn_fdot2(__builtin_bit_cast(h2, q.y), w1, t, false);
#else
    float2 f0 = __half22float2(*reinterpret_cast<const __half2*>(&q.x));
    float2 f1 = __half22float2(*reinterpret_cast<const __half2*>(&q.y));
    float top = fmaf(dx, f1.x - f0.x, f0.x);
    float bot = fmaf(dx, f1.y - f0.y, f0.y);
    return fmaf(dy, bot - top, top);
#endif
}

// ROUND-8 PROVEN proj body (79 us), byte-identical (cosf in-kernel).
__global__ __launch_bounds__(256) void k_proj5(const unsigned int* __restrict__ RP,
                                               float* __restrict__ partial) {
    int wave_id = blockIdx.x * 4 + (threadIdx.x >> 6);
    int lane = threadIdx.x & 63;
    int lx = lane & 7;
    int ly = lane >> 3;

    int xs = wave_id % XS_N;
    int t  = wave_id / XS_N;
    int a  = t & (NA - 1);
    int chunk = t >> 6;

    int X0 = xs * 8;
    int X = X0 + lx;

    float fa = (float)a;
    float c = cosf(fa);
    float s = sinf(fa);
    float bx = -CENTER * (c + s - 1.0f);
    float by = -CENTER * (c - s - 1.0f);
    float cx0 = fmaf(c, (float)X, bx);      // x_in = cx0 + s*Y  (unshifted)
    float cy0 = fmaf(-s, (float)X, by);     // y_in = cy0 + c*Y
    float cxs = cx0 + (float)PW;            // shifted (edge path)
    float cys = cy0 + (float)PW;

    int oct_beg = (chunk * XS_N) / YS;
    int oct_end = ((chunk + 1) * XS_N) / YS;
    int noct = oct_end - oct_beg;

    // ---- per-oct classification (lane l <-> oct_beg+l), proven r4-r8 ----
    float ab = fabsf(c) + fabsf(s);
    float E = fmaf(3.5f, ab, 2.0f);
    float D = 3.5f * ab;
    float xcw = fmaf(c, (float)X0 + 3.5f, bx);
    float ycw = fmaf(-s, (float)X0 + 3.5f, by);
    float ycen = (float)((oct_beg + lane) * 8) + 3.5f;
    float xcf = fmaf(s, ycen, xcw);
    float ycf = fmaf(c, ycen, ycw);
    float uxf = xcf - 211.0f + E + 1449.0f;
    float uyf = ycf - 211.0f + E + 1449.0f;
    unsigned iux = (unsigned)uxf;
    unsigned iuy = (unsigned)uyf;
    unsigned mxr = iux - __umul24(__umul24(iux, 11581u) >> 24, 1449u);
    unsigned myr = iuy - __umul24(__umul24(iuy, 11581u) >> 24, 1449u);
    unsigned lim = (unsigned)(1026.0f + 2.0f * E);
    bool act = (lane < noct) && (mxr <= lim) && (myr <= lim);
    bool interior = (xcf - D >= 213.0f) && (xcf + D <= 1234.0f) &&
                    (ycf - D >= 213.0f) && (ycf + D <= 1234.0f);
    unsigned long long mask_int  = __ballot(act && interior);
    unsigned long long mask_edge = __ballot(act && !interior);

    float fly = (float)ly;
    float acc = 0.0f;

    // ---- interior fast path: no mod, no bounds, trunc=floor ----
    while (mask_int) {
        int tb = (int)__builtin_ctzll(mask_int);
        mask_int &= mask_int - 1;
        float yb = (float)((oct_beg + tb) << 3);
        float yf = yb + fly;
        float x_in = fmaf(s, yf, cx0);
        float y_in = fmaf(c, yf, cy0);
        int ix = (int)x_in;                 // positive -> trunc == floor
        int iy = (int)y_in;
        float dx = x_in - (float)ix;
        float dy = y_in - (float)iy;
        unsigned idx = __umul24((unsigned)iy, PWS) + (unsigned)ix;
        uint2 q = *reinterpret_cast<const uint2*>(RP + idx);
        acc = blend4(q, dx, dy, acc);
    }

    // ---- edge path: exact wrap + bounds (loads always in-buffer) ----
    while (mask_edge) {
        int tb = (int)__builtin_ctzll(mask_edge);
        mask_edge &= mask_edge - 1;
        float yb = (float)((oct_beg + tb) << 3);
        float yf = yb + fly;
        float x_s = fmaf(s, yf, cxs);
        float y_s = fmaf(c, yf, cys);
        int ixs = (int)x_s;                 // positive (>=424) -> trunc == floor
        int iys = (int)y_s;
        float dx = x_s - (float)ixs;
        float dy = y_s - (float)iys;
        unsigned vx = (unsigned)ixs;        // [424, 3922) — mul24-safe
        unsigned vy = (unsigned)iys;
        unsigned x0 = vx - __umul24(__umul24(vx, 11581u) >> 24, 1449u);
        unsigned y0 = vy - __umul24(__umul24(vy, 11581u) >> 24, 1449u);
        bool ok = ((x0 - (PAD0 - 1)) <= 1024u) && ((y0 - (PAD0 - 1)) <= 1024u);
        unsigned idx = __umul24(y0, PWS) + x0;
        uint2 q = *reinterpret_cast<const uint2*>(RP + idx);
        float contrib = blend4_val(q, dx, dy);
        acc += ok ? contrib : 0.0f;
    }

    acc += __shfl_xor(acc, 8, 64);
    acc += __shfl_xor(acc, 16, 64);
    acc += __shfl_xor(acc, 32, 64);

    if (ly == 0) partial[(size_t)chunk * NOUT + a * OW + X] = acc;
}

// ---------- fused combine + transpose-write + per-block max (r10 proven) ----
// NOUT = 362*256 exactly: grid 362, no OOB threads.
__global__ __launch_bounds__(256) void k_combmax(const float* __restrict__ partial,
                                                 float* __restrict__ out,
                                                 float* __restrict__ bmax) {
    __shared__ float sm[4];
    int gid = blockIdx.x * 256 + threadIdx.x;
    float sum = 0.0f;
#pragma unroll
    for (int cth = 0; cth < YS; ++cth) sum += partial[(size_t)cth * NOUT + gid];
    int a = gid / OW;
    int x = gid - a * OW;
    out[x * NA + a] = sum;   // transpose: A = lines.T
    float m = sum;
#pragma unroll
    for (int off = 32; off > 0; off >>= 1) m = fmaxf(m, __shfl_down(m, off, 64));
    int lane = threadIdx.x & 63;
    int w = threadIdx.x >> 6;
    if (lane == 0) sm[w] = m;
    __syncthreads();
    if (threadIdx.x == 0)
        bmax[blockIdx.x] = fmaxf(fmaxf(sm[0], sm[1]), fmaxf(sm[2], sm[3]));
}

__global__ __launch_bounds__(256) void k_max2(const float* __restrict__ bmax,
                                              float* __restrict__ mx) {
    __shared__ float sm[4];
    float m = -3.4e38f;
    for (int i = threadIdx.x; i < 362; i += 256) m = fmaxf(m, bmax[i]);
#pragma unroll
    for (int off = 32; off > 0; off >>= 1) m = fmaxf(m, __shfl_down(m, off, 64));
    int lane = threadIdx.x & 63;
    int w = threadIdx.x >> 6;
    if (lane == 0) sm[w] = m;
    __syncthreads();
    if (threadIdx.x == 0)
        *mx = fmaxf(fmaxf(sm[0], sm[1]), fmaxf(sm[2], sm[3]));
}

__global__ __launch_bounds__(256) void k_norm(float* __restrict__ out,
                                              const float* __restrict__ mx) {
    int gid = blockIdx.x * blockDim.x + threadIdx.x;
    if (gid < NOUT) out[gid] = out[gid] / (*mx);
}

// ---------- round-5 proven fallback (fp32 P, float2 taps) ----------
__global__ __launch_bounds__(256) void k_pad_dwt(const float* __restrict__ img,
                                                 float* __restrict__ P) {
    int gid = blockIdx.x * blockDim.x + threadIdx.x;
    if (gid >= PW * PW) return;
    int r = gid / PW;
    int cidx = gid - r * PW;
    P[gid] = conv_at(img, r, cidx);
}

__global__ __launch_bounds__(256) void k_proj3(const float* __restrict__ P,
                                               float* __restrict__ partial) {
    int wave_id = blockIdx.x * 4 + (threadIdx.x >> 6);
    int lane = threadIdx.x & 63;
    int lx = lane & 7;
    int ly = lane >> 3;

    int xs = wave_id % XS_N;
    int t  = wave_id / XS_N;
    int a  = t & (NA - 1);
    int chunk = t >> 6;

    int X0 = xs * 8;
    int X = X0 + lx;

    float fa = (float)a;
    float c = cosf(fa);
    float s = sinf(fa);
    float bx = -CENTER * (c + s - 1.0f);
    float by = -CENTER * (c - s - 1.0f);
    float cxs = fmaf(c, (float)X, bx) + (float)PW;
    float cys = fmaf(-s, (float)X, by) + (float)PW;

    int oct_beg = (chunk * XS_N) / YS;
    int oct_end = ((chunk + 1) * XS_N) / YS;
    int noct = oct_end - oct_beg;

    float E = fmaf(3.5f, fabsf(c) + fabsf(s), 2.0f);
    float xcw = fmaf(c, (float)X0 + 3.5f, bx);
    float ycw = fmaf(-s, (float)X0 + 3.5f, by);
    float ycen = (float)((oct_beg + lane) * 8) + 3.5f;
    float uxf = fmaf(s, ycen, xcw) - 211.0f + E + 1449.0f;
    float uyf = fmaf(c, ycen, ycw) - 211.0f + E + 1449.0f;
    unsigned iux = (unsigned)uxf;
    unsigned iuy = (unsigned)uyf;
    unsigned mxr = iux - ((iux * 11581u) >> 24) * 1449u;
    unsigned myr = iuy - ((iuy * 11581u) >> 24) * 1449u;
    unsigned lim = (unsigned)(1026.0f + 2.0f * E);
    bool act = (lane < noct) && (mxr <= lim) && (myr <= lim);
    unsigned long long mask = __ballot(act);

    float acc = 0.0f;
    while (mask) {
        int tb = (int)__builtin_ctzll(mask);
        mask &= mask - 1;
        float yf = (float)(((oct_beg + tb) << 3) + ly);
        float x_s = fmaf(s, yf, cxs);
        float y_s = fmaf(c, yf, cys);
        float fx = floorf(x_s);
        float fy = floorf(y_s);
        float dx = x_s - fx;
        float dy = y_s - fy;
        unsigned vx = (unsigned)fx;
        unsigned vy = (unsigned)fy;
        int x0 = (int)(vx - ((vx * 11581u) >> 24) * 1449u);
        int y0 = (int)(vy - ((vy * 11581u) >> 24) * 1449u);
        bool ok = ((unsigned)(x0 - (PAD0 - 1)) <= 1024u) &&
                  ((unsigned)(y0 - (PAD0 - 1)) <= 1024u);
        const float* p0 = P + (y0 * PW + x0);
        float2 tv = *reinterpret_cast<const float2*>(p0);
        float2 bv = *reinterpret_cast<const float2*>(p0 + PW);
        float top = fmaf(dx, tv.y - tv.x, tv.x);
        float bot = fmaf(dx, bv.y - bv.x, bv.x);
        float contrib = fmaf(dy, bot - top, top);
        acc += ok ? contrib : 0.0f;
    }

    acc += __shfl_xor(acc, 8, 64);
    acc += __shfl_xor(acc, 16, 64);
    acc += __shfl_xor(acc, 32, 64);

    if (ly == 0) partial[(size_t)chunk * NOUT + a * OW + X] = acc;
}

extern "C" void kernel_launch(void* const* d_in, const int* in_sizes, int n_in,
                              void* d_out, int out_size, void* d_ws, size_t ws_size,
                              hipStream_t stream) {
    const float* img = (const float*)d_in[0];
    float* out = (float*)d_out;

    const size_t need_new = (NRP + 16) * 4 + ((size_t)YS * NOUT + 512 + 1) * 4;
    const size_t np_alloc = NPAD + PW + 8;
    const size_t need_old = np_alloc * 4 + ((size_t)YS * NOUT + 512 + 1) * 4;

    if (ws_size >= need_new) {
        unsigned int* RP = (unsigned int*)d_ws;
        float* partial = (float*)(RP + NRP + 16);
        float* bmax = partial + (size_t)YS * NOUT;   // 512 slots
        float* mx = bmax + 512;
        k_pack<<<(int)((NRP + 255) / 256), 256, 0, stream>>>(img, RP);
        k_proj5<<<NBLOCKS, 256, 0, stream>>>(RP, partial);
        k_combmax<<<NOUT / 256, 256, 0, stream>>>(partial, out, bmax);
        k_max2<<<1, 256, 0, stream>>>(bmax, mx);
        k_norm<<<(NOUT + 255) / 256, 256, 0, stream>>>(out, mx);
    } else if (ws_size >= need_old) {
        float* P = (float*)d_ws;
        float* partial = P + np_alloc;
        float* bmax = partial + (size_t)YS * NOUT;
        float* mx = bmax + 512;
        k_pad_dwt<<<(int)((NPAD + 255) / 256), 256, 0, stream>>>(img, P);
        k_proj3<<<NBLOCKS, 256, 0, stream>>>(P, partial);
        k_combmax<<<NOUT / 256, 256, 0, stream>>>(partial, out, bmax);
        k_max2<<<1, 256, 0, stream>>>(bmax, mx);
        k_norm<<<(NOUT + 255) / 256, 256, 0, stream>>>(out, mx);
    }
}